// Round 1
// baseline (2485.355 us; speedup 1.0000x reference)
//
#include <hip/hip_runtime.h>
#include <math.h>

#define NN 50000
#define EE 800000
#define FIN 100
#define HH 64
#define CC 18

// ---------------- p = x @ fW1  (no bias; bias folded after aggregation) ----
__global__ __launch_bounds__(256) void k_gemm_first(
    const float* __restrict__ x, const float* __restrict__ W,
    float* __restrict__ p) {
  __shared__ float Ws[FIN * HH];   // 25.6 KB
  __shared__ float xs[64 * FIN];   // 25.6 KB
  int t = threadIdx.x;
  for (int i = t; i < FIN * HH; i += 256) Ws[i] = W[i];
  int n0 = blockIdx.x * 64;
  for (int i = t; i < 64 * FIN; i += 256) {
    int r = i / FIN, c = i - r * FIN;
    int n = n0 + r;
    xs[i] = (n < NN) ? x[n * FIN + c] : 0.f;
  }
  __syncthreads();
  int j = t & 63, nl = t >> 6;
  float acc[16];
#pragma unroll
  for (int q = 0; q < 16; ++q) acc[q] = 0.f;
  for (int k = 0; k < FIN; ++k) {
    float w = Ws[k * HH + j];
#pragma unroll
    for (int q = 0; q < 16; ++q)
      acc[q] = fmaf(xs[(nl + q * 4) * FIN + k], w, acc[q]);
  }
#pragma unroll
  for (int q = 0; q < 16; ++q) {
    int n = n0 + nl + q * 4;
    if (n < NN) p[n * HH + j] = acc[q];
  }
}

// ---------------- agg[dst] += feat[src]  (atomic scatter) ------------------
__global__ __launch_bounds__(256) void k_scatter(
    const int* __restrict__ ei, const float* __restrict__ feat,
    float* __restrict__ agg) {
  const int total = EE * 16;  // each item: one float4 chunk of one edge
  for (int w = blockIdx.x * 256 + threadIdx.x; w < total;
       w += gridDim.x * 256) {
    int e = w >> 4;
    int q = (w & 15) << 2;
    int s = ei[e];
    int d = ei[EE + e];
    const float4 v = *reinterpret_cast<const float4*>(feat + s * HH + q);
    float* dp = agg + d * HH + q;
    atomicAdd(dp + 0, v.x);
    atomicAdd(dp + 1, v.y);
    atomicAdd(dp + 2, v.z);
    atomicAdd(dp + 3, v.w);
  }
}

// -------- first conv tail: z=(1+e)p+agg+b1; relu; @W2+b2; relu; BN ---------
__global__ __launch_bounds__(256) void k_mlp_first(
    const float* __restrict__ p, const float* __restrict__ agg,
    const float* __restrict__ epsv, const float* __restrict__ b1,
    const float* __restrict__ W2, const float* __restrict__ b2,
    const float* __restrict__ g, const float* __restrict__ be,
    const float* __restrict__ mu, const float* __restrict__ var,
    float* __restrict__ out) {
  __shared__ float W2s[HH * HH];  // 16 KB
  int t = threadIdx.x;
  for (int i = t; i < HH * HH; i += 256) W2s[i] = W2[i];
  __syncthreads();
  int j = t & 63, wv = t >> 6;
  float e0 = 1.f + epsv[0];
  float b1j = b1[j], b2j = b2[j];
  float sj = g[j] * rsqrtf(var[j] + 1e-5f);
  float bj = be[j] - mu[j] * sj;
  int wave = blockIdx.x * 4 + wv;
  int nw = gridDim.x * 4;
  for (int n = wave; n < NN; n += nw) {
    float a = fmaf(e0, p[n * HH + j], agg[n * HH + j]) + b1j;
    float tv = fmaxf(a, 0.f);
    float u = b2j;
#pragma unroll
    for (int k = 0; k < HH; ++k)
      u = fmaf(__shfl(tv, k), W2s[k * HH + j], u);
    float h = fmaxf(u, 0.f);
    out[n * HH + j] = fmaf(h, sj, bj);
  }
}

// -------- GIN layer tail: z=(1+e)h+agg; relu(z@W1+b1)@W2+b2; relu; BN ------
__global__ __launch_bounds__(256) void k_layer(
    const float* __restrict__ h, const float* __restrict__ agg,
    const float* __restrict__ epsv, const float* __restrict__ W1,
    const float* __restrict__ b1, const float* __restrict__ W2,
    const float* __restrict__ b2, const float* __restrict__ g,
    const float* __restrict__ be, const float* __restrict__ mu,
    const float* __restrict__ var, float* __restrict__ out) {
  __shared__ float W1s[HH * HH];
  __shared__ float W2s[HH * HH];  // 32 KB total
  int t = threadIdx.x;
  for (int i = t; i < HH * HH; i += 256) {
    W1s[i] = W1[i];
    W2s[i] = W2[i];
  }
  __syncthreads();
  int j = t & 63, wv = t >> 6;
  float e0 = 1.f + epsv[0];
  float b1j = b1[j], b2j = b2[j];
  float sj = g[j] * rsqrtf(var[j] + 1e-5f);
  float bj = be[j] - mu[j] * sj;
  int wave = blockIdx.x * 4 + wv;
  int nw = gridDim.x * 4;
  for (int n = wave; n < NN; n += nw) {
    float z = fmaf(e0, h[n * HH + j], agg[n * HH + j]);
    float tv = b1j;
#pragma unroll
    for (int k = 0; k < HH; ++k)
      tv = fmaf(__shfl(z, k), W1s[k * HH + j], tv);
    tv = fmaxf(tv, 0.f);
    float u = b2j;
#pragma unroll
    for (int k = 0; k < HH; ++k)
      u = fmaf(__shfl(tv, k), W2s[k * HH + j], u);
    float hv = fmaxf(u, 0.f);
    out[n * HH + j] = fmaf(hv, sj, bj);
  }
}

// -------- readout: relu(h@L1+b)@L2+b2 -> log_softmax -----------------------
__global__ __launch_bounds__(256) void k_readout(
    const float* __restrict__ h, const float* __restrict__ W1,
    const float* __restrict__ b1, const float* __restrict__ W2,
    const float* __restrict__ b2, float* __restrict__ out) {
  __shared__ float W1s[HH * HH];
  __shared__ float W2s[HH * CC + 64];  // pad: lanes >=18 read garbage, masked
  int t = threadIdx.x;
  for (int i = t; i < HH * HH; i += 256) W1s[i] = W1[i];
  for (int i = t; i < HH * CC; i += 256) W2s[i] = W2[i];
  __syncthreads();
  int j = t & 63, wv = t >> 6;
  float b1j = b1[j];
  float b2j = (j < CC) ? b2[j] : 0.f;
  int wave = blockIdx.x * 4 + wv;
  int nw = gridDim.x * 4;
  for (int n = wave; n < NN; n += nw) {
    float hv = h[n * HH + j];
    float r = b1j;
#pragma unroll
    for (int k = 0; k < HH; ++k)
      r = fmaf(__shfl(hv, k), W1s[k * HH + j], r);
    r = fmaxf(r, 0.f);
    float o = b2j;
#pragma unroll
    for (int k = 0; k < HH; ++k) {
      float rk = __shfl(r, k);
      o = fmaf(rk, W2s[k * CC + j], o);  // lanes >=18 compute garbage, masked
    }
    float om = (j < CC) ? o : -3.4e38f;
    float mx = om;
#pragma unroll
    for (int m = 32; m >= 1; m >>= 1) mx = fmaxf(mx, __shfl_xor(mx, m));
    float ex = (j < CC) ? expf(o - mx) : 0.f;
    float sm = ex;
#pragma unroll
    for (int m = 32; m >= 1; m >>= 1) sm += __shfl_xor(sm, m);
    if (j < CC) out[n * CC + j] = o - mx - logf(sm);
  }
}

extern "C" void kernel_launch(void* const* d_in, const int* in_sizes, int n_in,
                              void* d_out, int out_size, void* d_ws,
                              size_t ws_size, hipStream_t stream) {
  const float* x = (const float*)d_in[0];
  const int* ei = (const int*)d_in[1];
  const float* eps = (const float*)d_in[2];
  const float* fW1 = (const float*)d_in[3];
  const float* fb1 = (const float*)d_in[4];
  const float* fW2 = (const float*)d_in[5];
  const float* fb2 = (const float*)d_in[6];
  const float* W1s = (const float*)d_in[7];
  const float* b1s = (const float*)d_in[8];
  const float* W2s = (const float*)d_in[9];
  const float* b2s = (const float*)d_in[10];
  const float* bn_g = (const float*)d_in[11];
  const float* bn_b = (const float*)d_in[12];
  const float* bn_m = (const float*)d_in[13];
  const float* bn_v = (const float*)d_in[14];
  const float* l1W = (const float*)d_in[15];
  const float* l1b = (const float*)d_in[16];
  const float* l2W = (const float*)d_in[17];
  const float* l2b = (const float*)d_in[18];
  float* out = (float*)d_out;

  const size_t NH = (size_t)NN * HH;
  float* buf0 = (float*)d_ws;          // p / h
  float* buf1 = buf0 + NH;             // agg
  float* buf2 = buf1 + NH;             // h alt

  // 1) p = x @ fW1
  k_gemm_first<<<(NN + 63) / 64, 256, 0, stream>>>(x, fW1, buf0);

  // 2) first conv aggregation + tail -> buf2 (h0)
  hipMemsetAsync(buf1, 0, NH * sizeof(float), stream);
  k_scatter<<<4096, 256, 0, stream>>>(ei, buf0, buf1);
  k_mlp_first<<<1024, 256, 0, stream>>>(buf0, buf1, eps + 0, fb1, fW2, fb2,
                                        bn_g, bn_b, bn_m, bn_v, buf2);

  // 3) layer 0: buf2 -> buf0
  hipMemsetAsync(buf1, 0, NH * sizeof(float), stream);
  k_scatter<<<4096, 256, 0, stream>>>(ei, buf2, buf1);
  k_layer<<<1024, 256, 0, stream>>>(buf2, buf1, eps + 1, W1s, b1s, W2s, b2s,
                                    bn_g + HH, bn_b + HH, bn_m + HH,
                                    bn_v + HH, buf0);

  // 4) layer 1: buf0 -> buf2
  hipMemsetAsync(buf1, 0, NH * sizeof(float), stream);
  k_scatter<<<4096, 256, 0, stream>>>(ei, buf0, buf1);
  k_layer<<<1024, 256, 0, stream>>>(buf0, buf1, eps + 2, W1s + HH * HH,
                                    b1s + HH, W2s + HH * HH, b2s + HH,
                                    bn_g + 2 * HH, bn_b + 2 * HH,
                                    bn_m + 2 * HH, bn_v + 2 * HH, buf2);

  // 5) readout -> out
  k_readout<<<1024, 256, 0, stream>>>(buf2, l1W, l1b, l2W, l2b, out);
}

// Round 2
// 665.418 us; speedup vs baseline: 3.7350x; 3.7350x over previous
//
#include <hip/hip_runtime.h>
#include <math.h>

#define NN 50000
#define EE 800000
#define FIN 100
#define HH 64
#define CC 18

// ---------------- p = x @ fW1  (no bias; bias folded after aggregation) ----
__global__ __launch_bounds__(256) void k_gemm_first(
    const float* __restrict__ x, const float* __restrict__ W,
    float* __restrict__ p) {
  __shared__ float Ws[FIN * HH];   // 25.6 KB
  __shared__ float xs[64 * FIN];   // 25.6 KB
  int t = threadIdx.x;
  for (int i = t; i < FIN * HH; i += 256) Ws[i] = W[i];
  int n0 = blockIdx.x * 64;
  for (int i = t; i < 64 * FIN; i += 256) {
    int r = i / FIN, c = i - r * FIN;
    int n = n0 + r;
    xs[i] = (n < NN) ? x[n * FIN + c] : 0.f;
  }
  __syncthreads();
  int j = t & 63, nl = t >> 6;
  float acc[16];
#pragma unroll
  for (int q = 0; q < 16; ++q) acc[q] = 0.f;
  for (int k = 0; k < FIN; ++k) {
    float w = Ws[k * HH + j];
#pragma unroll
    for (int q = 0; q < 16; ++q)
      acc[q] = fmaf(xs[(nl + q * 4) * FIN + k], w, acc[q]);
  }
#pragma unroll
  for (int q = 0; q < 16; ++q) {
    int n = n0 + nl + q * 4;
    if (n < NN) p[n * HH + j] = acc[q];
  }
}

// ---------------- CSR build ------------------------------------------------
__global__ __launch_bounds__(256) void k_count(const int* __restrict__ ei,
                                               int* __restrict__ counts) {
  for (int e = blockIdx.x * 256 + threadIdx.x; e < EE; e += gridDim.x * 256)
    atomicAdd(&counts[ei[EE + e]], 1);
}

// single block, 1024 threads: exclusive scan of counts -> rowptr, cursor
__global__ __launch_bounds__(1024) void k_scan(const int* __restrict__ counts,
                                               int* __restrict__ rowptr,
                                               int* __restrict__ cursor) {
  __shared__ int wtot[16];
  __shared__ int woff[17];
  int t = threadIdx.x;
  int lane = t & 63, wid = t >> 6;
  int running = 0;
  for (int c0 = 0; c0 < NN; c0 += 1024) {
    int idx = c0 + t;
    int v = (idx < NN) ? counts[idx] : 0;
    // wave-inclusive scan (no syncs)
    int x = v;
#pragma unroll
    for (int off = 1; off < 64; off <<= 1) {
      int y = __shfl_up(x, off);
      if (lane >= off) x += y;
    }
    if (lane == 63) wtot[wid] = x;
    __syncthreads();
    if (wid == 0 && lane < 16) {
      int w = wtot[lane];
      int xs = w;
#pragma unroll
      for (int off = 1; off < 16; off <<= 1) {
        int y = __shfl_up(xs, off);
        if (lane >= off) xs += y;
      }
      woff[lane] = xs - w;            // exclusive wave offset
      if (lane == 15) woff[16] = xs;  // chunk total
    }
    __syncthreads();
    int excl = x - v + woff[wid];
    if (idx < NN) {
      rowptr[idx] = running + excl;
      cursor[idx] = running + excl;
    }
    int total = woff[16];
    __syncthreads();
    running += total;
  }
  if (t == 0) rowptr[NN] = running;
}

__global__ __launch_bounds__(256) void k_fill(const int* __restrict__ ei,
                                              int* __restrict__ cursor,
                                              int* __restrict__ eidx) {
  for (int e = blockIdx.x * 256 + threadIdx.x; e < EE; e += gridDim.x * 256) {
    int s = ei[e], d = ei[EE + e];
    int pos = atomicAdd(&cursor[d], 1);
    eidx[pos] = s;
  }
}

// ---------------- gather helper: sum feat[src][j] over in-edges ------------
__device__ __forceinline__ float gather_sum(const float* __restrict__ feat,
                                            const int* __restrict__ eidx,
                                            int beg, int end, int j) {
  float agg = 0.f;
  for (int i0 = beg; i0 < end; i0 += 64) {
    int cnt = min(end - i0, 64);
    int eid = (j < cnt) ? eidx[i0 + j] : 0;
    int k = 0;
    for (; k + 4 <= cnt; k += 4) {
      int s0 = __shfl(eid, k), s1 = __shfl(eid, k + 1);
      int s2 = __shfl(eid, k + 2), s3 = __shfl(eid, k + 3);
      float a0 = feat[s0 * HH + j], a1 = feat[s1 * HH + j];
      float a2 = feat[s2 * HH + j], a3 = feat[s3 * HH + j];
      agg += (a0 + a1) + (a2 + a3);
    }
    for (; k < cnt; ++k) agg += feat[__shfl(eid, k) * HH + j];
  }
  return agg;
}

// -------- first conv: agg=gather(p); z=(1+e)p+agg+b1; relu; @W2+b2; relu; BN
__global__ __launch_bounds__(256) void k_first(
    const float* __restrict__ p, const int* __restrict__ rowptr,
    const int* __restrict__ eidx, const float* __restrict__ epsv,
    const float* __restrict__ b1, const float* __restrict__ W2,
    const float* __restrict__ b2, const float* __restrict__ g,
    const float* __restrict__ be, const float* __restrict__ mu,
    const float* __restrict__ var, float* __restrict__ out) {
  __shared__ float W2s[HH * HH];  // 16 KB
  int t = threadIdx.x;
  for (int i = t; i < HH * HH; i += 256) W2s[i] = W2[i];
  __syncthreads();
  int j = t & 63, wv = t >> 6;
  float e0 = 1.f + epsv[0];
  float b1j = b1[j], b2j = b2[j];
  float sj = g[j] * rsqrtf(var[j] + 1e-5f);
  float bj = be[j] - mu[j] * sj;
  int wave = blockIdx.x * 4 + wv;
  int nw = gridDim.x * 4;
  for (int n = wave; n < NN; n += nw) {
    int beg = rowptr[n], end = rowptr[n + 1];
    float agg = gather_sum(p, eidx, beg, end, j);
    float a = fmaf(e0, p[n * HH + j], agg) + b1j;
    float tv = fmaxf(a, 0.f);
    float u = b2j;
#pragma unroll
    for (int k = 0; k < HH; ++k)
      u = fmaf(__shfl(tv, k), W2s[k * HH + j], u);
    float h = fmaxf(u, 0.f);
    out[n * HH + j] = fmaf(h, sj, bj);
  }
}

// -------- GIN layer: agg=gather(h); relu(z@W1+b1)@W2+b2; relu; BN ----------
__global__ __launch_bounds__(256) void k_layer(
    const float* __restrict__ h, const int* __restrict__ rowptr,
    const int* __restrict__ eidx, const float* __restrict__ epsv,
    const float* __restrict__ W1, const float* __restrict__ b1,
    const float* __restrict__ W2, const float* __restrict__ b2,
    const float* __restrict__ g, const float* __restrict__ be,
    const float* __restrict__ mu, const float* __restrict__ var,
    float* __restrict__ out) {
  __shared__ float W1s[HH * HH];
  __shared__ float W2s[HH * HH];  // 32 KB total
  int t = threadIdx.x;
  for (int i = t; i < HH * HH; i += 256) {
    W1s[i] = W1[i];
    W2s[i] = W2[i];
  }
  __syncthreads();
  int j = t & 63, wv = t >> 6;
  float e0 = 1.f + epsv[0];
  float b1j = b1[j], b2j = b2[j];
  float sj = g[j] * rsqrtf(var[j] + 1e-5f);
  float bj = be[j] - mu[j] * sj;
  int wave = blockIdx.x * 4 + wv;
  int nw = gridDim.x * 4;
  for (int n = wave; n < NN; n += nw) {
    int beg = rowptr[n], end = rowptr[n + 1];
    float agg = gather_sum(h, eidx, beg, end, j);
    float z = fmaf(e0, h[n * HH + j], agg);
    float tv = b1j;
#pragma unroll
    for (int k = 0; k < HH; ++k)
      tv = fmaf(__shfl(z, k), W1s[k * HH + j], tv);
    tv = fmaxf(tv, 0.f);
    float u = b2j;
#pragma unroll
    for (int k = 0; k < HH; ++k)
      u = fmaf(__shfl(tv, k), W2s[k * HH + j], u);
    float hv = fmaxf(u, 0.f);
    out[n * HH + j] = fmaf(hv, sj, bj);
  }
}

// -------- readout: relu(h@L1+b)@L2+b2 -> log_softmax -----------------------
__global__ __launch_bounds__(256) void k_readout(
    const float* __restrict__ h, const float* __restrict__ W1,
    const float* __restrict__ b1, const float* __restrict__ W2,
    const float* __restrict__ b2, float* __restrict__ out) {
  __shared__ float W1s[HH * HH];
  __shared__ float W2s[HH * CC + 64];
  int t = threadIdx.x;
  for (int i = t; i < HH * HH; i += 256) W1s[i] = W1[i];
  for (int i = t; i < HH * CC + 64; i += 256)
    W2s[i] = (i < HH * CC) ? W2[i] : 0.f;
  __syncthreads();
  int j = t & 63, wv = t >> 6;
  float b1j = b1[j];
  float b2j = (j < CC) ? b2[j] : 0.f;
  int wave = blockIdx.x * 4 + wv;
  int nw = gridDim.x * 4;
  for (int n = wave; n < NN; n += nw) {
    float hv = h[n * HH + j];
    float r = b1j;
#pragma unroll
    for (int k = 0; k < HH; ++k)
      r = fmaf(__shfl(hv, k), W1s[k * HH + j], r);
    r = fmaxf(r, 0.f);
    float o = b2j;
#pragma unroll
    for (int k = 0; k < HH; ++k) {
      float rk = __shfl(r, k);
      o = fmaf(rk, W2s[k * CC + j], o);  // lanes >=18 compute garbage, masked
    }
    float om = (j < CC) ? o : -3.4e38f;
    float mx = om;
#pragma unroll
    for (int m = 32; m >= 1; m >>= 1) mx = fmaxf(mx, __shfl_xor(mx, m));
    float ex = (j < CC) ? expf(o - mx) : 0.f;
    float sm = ex;
#pragma unroll
    for (int m = 32; m >= 1; m >>= 1) sm += __shfl_xor(sm, m);
    if (j < CC) out[n * CC + j] = o - mx - logf(sm);
  }
}

extern "C" void kernel_launch(void* const* d_in, const int* in_sizes, int n_in,
                              void* d_out, int out_size, void* d_ws,
                              size_t ws_size, hipStream_t stream) {
  const float* x = (const float*)d_in[0];
  const int* ei = (const int*)d_in[1];
  const float* eps = (const float*)d_in[2];
  const float* fW1 = (const float*)d_in[3];
  const float* fb1 = (const float*)d_in[4];
  const float* fW2 = (const float*)d_in[5];
  const float* fb2 = (const float*)d_in[6];
  const float* W1s = (const float*)d_in[7];
  const float* b1s = (const float*)d_in[8];
  const float* W2s = (const float*)d_in[9];
  const float* b2s = (const float*)d_in[10];
  const float* bn_g = (const float*)d_in[11];
  const float* bn_b = (const float*)d_in[12];
  const float* bn_m = (const float*)d_in[13];
  const float* bn_v = (const float*)d_in[14];
  const float* l1W = (const float*)d_in[15];
  const float* l1b = (const float*)d_in[16];
  const float* l2W = (const float*)d_in[17];
  const float* l2b = (const float*)d_in[18];
  float* out = (float*)d_out;

  // ws layout (elements):
  //   eidx[EE] | counts[NN] | cursor[NN] | rowptr[NN+1] | pad | buf0[NH] | buf2[NH]
  int* eidx = (int*)d_ws;
  int* counts = eidx + EE;
  int* cursor = counts + NN;
  int* rowptr = cursor + NN;
  size_t int_elems = (size_t)EE + NN + NN + NN + 1;
  size_t f_off = (int_elems + 3) & ~(size_t)3;  // 16B align
  const size_t NH = (size_t)NN * HH;
  float* buf0 = (float*)d_ws + f_off;  // p / h
  float* buf2 = buf0 + NH;             // h alt

  // CSR build (edge_index is identical every call; rebuilt each call anyway)
  hipMemsetAsync(counts, 0, NN * sizeof(int), stream);
  k_count<<<2048, 256, 0, stream>>>(ei, counts);
  k_scan<<<1, 1024, 0, stream>>>(counts, rowptr, cursor);
  k_fill<<<2048, 256, 0, stream>>>(ei, cursor, eidx);

  // 1) p = x @ fW1
  k_gemm_first<<<(NN + 63) / 64, 256, 0, stream>>>(x, fW1, buf0);

  // 2) first conv (gather fused) -> buf2 (h0)
  k_first<<<1024, 256, 0, stream>>>(buf0, rowptr, eidx, eps + 0, fb1, fW2,
                                    fb2, bn_g, bn_b, bn_m, bn_v, buf2);

  // 3) layer 0: buf2 -> buf0
  k_layer<<<1024, 256, 0, stream>>>(buf2, rowptr, eidx, eps + 1, W1s, b1s,
                                    W2s, b2s, bn_g + HH, bn_b + HH,
                                    bn_m + HH, bn_v + HH, buf0);

  // 4) layer 1: buf0 -> buf2
  k_layer<<<1024, 256, 0, stream>>>(buf0, rowptr, eidx, eps + 2,
                                    W1s + HH * HH, b1s + HH, W2s + HH * HH,
                                    b2s + HH, bn_g + 2 * HH, bn_b + 2 * HH,
                                    bn_m + 2 * HH, bn_v + 2 * HH, buf2);

  // 5) readout -> out
  k_readout<<<1024, 256, 0, stream>>>(buf2, l1W, l1b, l2W, l2b, out);
}